// Round 12
// baseline (291.171 us; speedup 1.0000x reference)
//
#include <hip/hip_runtime.h>
#include <hip/hip_bf16.h>
#include <cstdint>
#include <cstddef>

#define S_LEN  1024
#define DMODEL 1024
#define NHEAD  16
#define HDIM   64
#define BATCH  4
#define MROWS  (BATCH * S_LEN)   // 4096

typedef __bf16 bf16;
typedef __attribute__((ext_vector_type(8))) __bf16 bf16x8;
typedef __attribute__((ext_vector_type(4))) __bf16 bf16x4;
typedef __attribute__((ext_vector_type(4))) float f32x4;
typedef __attribute__((ext_vector_type(4))) unsigned int u32x4;

// ---------------------------------------------------------------------------
__device__ __forceinline__ void async_load16(const void* g, void* l) {
    __builtin_amdgcn_global_load_lds(
        (const __attribute__((address_space(1))) unsigned int*)g,
        (__attribute__((address_space(3))) unsigned int*)l,
        16, 0, 0);
}

// ---------------------------------------------------------------------------
// Prep: blocks [0,8192) convert fr/en f32->bf16; [8192,13312) transpose
// W_attn and W_KV only (W_Q/W1/W2 transposes ride inside gemm_dual's launch).
__global__ __launch_bounds__(256)
void prep_all(const float* __restrict__ fr, bf16* __restrict__ fr_bf,
              const float* __restrict__ en, bf16* __restrict__ en_bf,
              const float* __restrict__ Wa, bf16* __restrict__ Ta,
              const float* __restrict__ Wkv, bf16* __restrict__ Tkv) {
    __shared__ float t[32][33];
    int id = blockIdx.x;
    if (id < 8192) {
        const int n4 = MROWS * DMODEL / 4;
        int i = id * 256 + threadIdx.x;
        const float* in = fr; bf16* out = fr_bf;
        if (i >= n4) { i -= n4; in = en; out = en_bf; }
        f32x4 v = ((const f32x4*)in)[i];
        bf16x4 o;
#pragma unroll
        for (int e = 0; e < 4; ++e) o[e] = (bf16)v[e];
        ((bf16x4*)out)[i] = o;
        return;
    }
    id -= 8192;
    const float* W; bf16* Wt; int K, N, nx, base;
    if (id < 3072) { W = Wa;  Wt = Ta;  K = 1024; N = 3072; nx = 96; base = 0; }
    else           { W = Wkv; Wt = Tkv; K = 1024; N = 2048; nx = 64; base = 3072; }
    int loc = id - base;
    int n0 = (loc % nx) * 32, k0 = (loc / nx) * 32;
    int tx = threadIdx.x & 31, ty = threadIdx.x >> 5;
#pragma unroll
    for (int j = 0; j < 4; ++j)
        t[ty + j * 8][tx] = W[(size_t)(k0 + ty + j * 8) * N + n0 + tx];
    __syncthreads();
#pragma unroll
    for (int j = 0; j < 4; ++j)
        Wt[(size_t)(n0 + ty + j * 8) * K + k0 + tx] = (bf16)t[tx][ty + j * 8];
}

// ---------------------------------------------------------------------------
// GEMM core BK=32: 128x128 tile, 4 waves (2x2), 2-buffer pipeline.
__device__ __forceinline__ void gemm_acc(const bf16* __restrict__ A,
                                         const bf16* __restrict__ Bt,
                                         int Klen, int lda, int ldb,
                                         bf16* Alds, bf16* Blds,  // each [2][128*32]
                                         f32x4 acc[4][4]) {
    const int tid = threadIdx.x;
    const int wave = tid >> 6, lane = tid & 63;
    const int wr = wave >> 1, wc = wave & 1;
    const int lr = lane & 15, lg = lane >> 4, lk = lg * 8;
    const int srow = lane >> 2, scol = (lane & 3) * 8;

    const bf16* Aw = A + (size_t)(wave * 32 + srow) * lda + scol;
    const bf16* Bw = Bt + (size_t)(wave * 32 + srow) * ldb + scol;
    const int ldsw = (wave * 32) * 32;

    async_load16(Aw, Alds + ldsw);
    async_load16(Aw + (size_t)16 * lda, Alds + ldsw + 16 * 32);
    async_load16(Bw, Blds + ldsw);
    async_load16(Bw + (size_t)16 * ldb, Blds + ldsw + 16 * 32);
    __syncthreads();

    const int nt = Klen >> 5;
    for (int t = 0; t < nt; ++t) {
        const int cur = t & 1;
        if (t + 1 < nt) {
            const size_t k0 = (size_t)(t + 1) << 5;
            bf16* Ad = Alds + (cur ^ 1) * (128 * 32) + ldsw;
            bf16* Bd = Blds + (cur ^ 1) * (128 * 32) + ldsw;
            async_load16(Aw + k0, Ad);
            async_load16(Aw + (size_t)16 * lda + k0, Ad + 16 * 32);
            async_load16(Bw + k0, Bd);
            async_load16(Bw + (size_t)16 * ldb + k0, Bd + 16 * 32);
        }
        const bf16* Ab = Alds + cur * (128 * 32);
        const bf16* Bb = Blds + cur * (128 * 32);
        bf16x8 af[4], bfv[4];
#pragma unroll
        for (int i = 0; i < 4; ++i) {
            af[i]  = *(const bf16x8*)&Ab[(wr * 64 + i * 16 + lr) * 32 + lk];
            bfv[i] = *(const bf16x8*)&Bb[(wc * 64 + i * 16 + lr) * 32 + lk];
        }
#pragma unroll
        for (int mi = 0; mi < 4; ++mi)
#pragma unroll
            for (int ni = 0; ni < 4; ++ni)
                acc[mi][ni] = __builtin_amdgcn_mfma_f32_16x16x32_bf16(
                    af[mi], bfv[ni], acc[mi][ni], 0, 0, 0);
        __syncthreads();
    }
}

// ---------------------------------------------------------------------------
// GEMM core BK=64: halves iterations (=barriers) vs BK=32. For kernels whose
// effective co-residency is <=2 blocks/CU anyway (64KB LDS is then free).
// LDS rows are 128B -> XOR-swizzle (pre-swizzled stage source, G4/rule #21).
__device__ __forceinline__ void gemm_acc64(const bf16* __restrict__ A,
                                           const bf16* __restrict__ Bt,
                                           int Klen, int lda, int ldb,
                                           bf16* Alds, bf16* Blds,  // each [2][128*64]
                                           f32x4 acc[4][4]) {
    const int tid = threadIdx.x;
    const int wave = tid >> 6, lane = tid & 63;
    const int wr = wave >> 1, wc = wave & 1;
    const int lr = lane & 15, lg = lane >> 4;
    const int srow = lane >> 3;             // 0..7 (row within 8-row group)
    const int sch = (lane & 7) ^ srow;      // pre-swizzled source chunk

    const bf16* Aw = A + (size_t)(wave * 32 + srow) * lda + sch * 8;
    const bf16* Bw = Bt + (size_t)(wave * 32 + srow) * ldb + sch * 8;

    const int nt = Klen >> 6;
#define STAGE64(buf, k0)                                                       \
    {                                                                          \
        bf16* Ad = Alds + (buf) * (128 * 64) + (wave * 32) * 64;               \
        bf16* Bd = Blds + (buf) * (128 * 64) + (wave * 32) * 64;               \
        _Pragma("unroll")                                                      \
        for (int j = 0; j < 4; ++j) {                                          \
            async_load16(Aw + (size_t)(j * 8) * lda + (k0), Ad + (j * 8) * 64);\
            async_load16(Bw + (size_t)(j * 8) * ldb + (k0), Bd + (j * 8) * 64);\
        }                                                                      \
    }

    STAGE64(0, 0);
    __syncthreads();

    for (int t = 0; t < nt; ++t) {
        const int cur = t & 1;
        if (t + 1 < nt) STAGE64(cur ^ 1, (size_t)(t + 1) << 6);
        const char* Ab = (const char*)(Alds + cur * (128 * 64));
        const char* Bb = (const char*)(Blds + cur * (128 * 64));
#pragma unroll
        for (int ks = 0; ks < 2; ++ks) {
            bf16x8 af[4], bfv[4];
#pragma unroll
            for (int i = 0; i < 4; ++i) {
                int ra = wr * 64 + i * 16 + lr;
                int rb = wc * 64 + i * 16 + lr;
                af[i] = *(const bf16x8*)(Ab + (size_t)ra * 128 +
                          ((ks * 64 + lg * 16) ^ ((ra & 7) << 4)));
                bfv[i] = *(const bf16x8*)(Bb + (size_t)rb * 128 +
                          ((ks * 64 + lg * 16) ^ ((rb & 7) << 4)));
            }
#pragma unroll
            for (int mi = 0; mi < 4; ++mi)
#pragma unroll
                for (int ni = 0; ni < 4; ++ni)
                    acc[mi][ni] = __builtin_amdgcn_mfma_f32_16x16x32_bf16(
                        af[mi], bfv[ni], acc[mi][ni], 0, 0, 0);
        }
        __syncthreads();
    }
#undef STAGE64
}

template<bool RELU>
__device__ __forceinline__ void epi_bf16(bf16* __restrict__ C, const float* __restrict__ bias,
                                         int N, int m0, int n0, f32x4 acc[4][4]) {
    const int tid = threadIdx.x;
    const int wave = tid >> 6, lane = tid & 63;
    const int wr = wave >> 1, wc = wave & 1;
    const int lr = lane & 15, lg = lane >> 4;
#pragma unroll
    for (int ni = 0; ni < 4; ++ni) {
        int n = n0 + wc * 64 + ni * 16 + lr;
        float bn = bias[n];
#pragma unroll
        for (int mi = 0; mi < 4; ++mi)
#pragma unroll
            for (int r = 0; r < 4; ++r) {
                int m = m0 + wr * 64 + mi * 16 + lg * 4 + r;
                float v = acc[mi][ni][r] + bn;
                if (RELU) v = v > 0.f ? v : 0.f;
                C[(size_t)m * N + n] = (bf16)v;
            }
    }
}

// M-tile skip: rows of this 128-tile are never consumed downstream.
__device__ __forceinline__ bool tile_dead(const int* Lm, int m0) {
    if (!Lm) return false;
    int cap = (Lm[m0 >> 10] + 63) & ~63;
    return (m0 & 1023) >= cap;
}

// N-major tile mapping (m0 = f%32, n0 = f/32): spreads tile_dead blocks
// uniformly across XCD chunks (see r9/r10 analysis).
template<bool RELU>
__global__ __launch_bounds__(256, 2)
void gemm_one(const bf16* __restrict__ A, const bf16* __restrict__ Bt,
              const float* __restrict__ bias, bf16* __restrict__ C,
              int N, int K, const int* __restrict__ Lm) {
    __shared__ alignas(16) bf16 Alds[2][128 * 32];
    __shared__ alignas(16) bf16 Blds[2][128 * 32];
    const int nwg = gridDim.x;
    const int flat = blockIdx.x;
    const int swz = (flat & 7) * (nwg >> 3) + (flat >> 3);
    const int m0 = (swz & 31) * 128, n0 = (swz >> 5) * 128;
    if (tile_dead(Lm, m0)) return;
    f32x4 acc[4][4] = {};
    gemm_acc(A + (size_t)m0 * K, Bt + (size_t)n0 * K, K, K, K,
             &Alds[0][0], &Blds[0][0], acc);
    epi_bf16<RELU>(C, bias, N, m0, n0, acc);
}

// BK=64 variant: for grids limited to <=2 blocks/CU (crossQ).
template<bool RELU>
__global__ __launch_bounds__(256, 2)
void gemm_one64(const bf16* __restrict__ A, const bf16* __restrict__ Bt,
                const float* __restrict__ bias, bf16* __restrict__ C,
                int N, int K, const int* __restrict__ Lm) {
    __shared__ alignas(16) bf16 Alds[2][128 * 64];
    __shared__ alignas(16) bf16 Blds[2][128 * 64];
    const int nwg = gridDim.x;
    const int flat = blockIdx.x;
    const int swz = (flat & 7) * (nwg >> 3) + (flat >> 3);
    const int m0 = (swz & 31) * 128, n0 = (swz >> 5) * 128;
    if (tile_dead(Lm, m0)) return;
    f32x4 acc[4][4] = {};
    gemm_acc64(A + (size_t)m0 * K, Bt + (size_t)n0 * K, K, K, K,
               &Alds[0][0], &Blds[0][0], acc);
    epi_bf16<RELU>(C, bias, N, m0, n0, acc);
}

// ---------------------------------------------------------------------------
// Dual GEMM (BK=64; live co-residency was ~2.5/CU at BK=32, so 64KB LDS is
// nearly free and barriers halve) + trailing weight-transpose blocks:
// flats [0,nwgG) = the two GEMMs; [nwgG,+9216) transpose W_Q/W1/W2.
struct GemmArgs {
    const bf16* A; const bf16* Bt; const float* bias; bf16* C;
    int N; int K; const int* Lm;
};
__global__ __launch_bounds__(256, 2)
void gemm_dual(GemmArgs g0, int nwg0, GemmArgs g1, int nwgG,
               const float* __restrict__ Wq, bf16* __restrict__ Tq,
               const float* __restrict__ W1, bf16* __restrict__ T1,
               const float* __restrict__ W2, bf16* __restrict__ T2) {
    __shared__ alignas(16) bf16 Alds[2][128 * 64];
    __shared__ alignas(16) bf16 Blds[2][128 * 64];
    const int flat = blockIdx.x;
    if (flat >= nwgG) {
        int id = flat - nwgG;
        const float* W; bf16* Wt; int K, N, nx, base;
        if (id < 1024)      { W = Wq; Wt = Tq; K = 1024; N = 1024; nx = 32;  base = 0; }
        else if (id < 5120) { W = W1; Wt = T1; K = 1024; N = 4096; nx = 128; base = 1024; }
        else                { W = W2; Wt = T2; K = 4096; N = 1024; nx = 32;  base = 5120; }
        int loc = id - base;
        int n0 = (loc % nx) * 32, k0 = (loc / nx) * 32;
        float (*t)[33] = (float(*)[33])&Alds[0][0];   // alias GEMM LDS
        int tx = threadIdx.x & 31, ty = threadIdx.x >> 5;
#pragma unroll
        for (int j = 0; j < 4; ++j)
            t[ty + j * 8][tx] = W[(size_t)(k0 + ty + j * 8) * N + n0 + tx];
        __syncthreads();
#pragma unroll
        for (int j = 0; j < 4; ++j)
            Wt[(size_t)(n0 + ty + j * 8) * K + k0 + tx] = (bf16)t[tx][ty + j * 8];
        return;
    }
    const int swz = (flat & 7) * (nwgG >> 3) + (flat >> 3);
    const bool first = swz < nwg0;
    const GemmArgs g = first ? g0 : g1;
    const int f = first ? swz : swz - nwg0;
    const int m0 = (f & 31) * 128, n0 = (f >> 5) * 128;
    if (tile_dead(g.Lm, m0)) return;
    f32x4 acc[4][4] = {};
    gemm_acc64(g.A + (size_t)m0 * g.K, g.Bt + (size_t)n0 * g.K, g.K, g.K, g.K,
               &Alds[0][0], &Blds[0][0], acc);
    epi_bf16<false>(g.C, g.bias, g.N, m0, n0, acc);
}

// ---------------------------------------------------------------------------
// Split-K=2 GEMM for FFN2, BK=64 core (grid 512 = 2 blocks/CU; 64KB LDS free).
__global__ __launch_bounds__(256, 2)
void gemm_splitk2(const bf16* __restrict__ A, const bf16* __restrict__ Bt,
                  float* __restrict__ P0, float* __restrict__ P1,
                  int N, int K, int nwg_half) {
    __shared__ alignas(16) bf16 Alds[2][128 * 64];
    __shared__ alignas(16) bf16 Blds[2][128 * 64];
    const int nwg = gridDim.x;
    const int flat = blockIdx.x;
    const int swz = (flat & 7) * (nwg >> 3) + (flat >> 3);
    const int kz = swz >= nwg_half ? 1 : 0;
    const int f = swz - kz * nwg_half;
    const int m0 = (f & 31) * 128, n0 = (f >> 5) * 128;
    const int Kh = K >> 1;
    const size_t koff = (size_t)kz * Kh;
    f32x4 acc[4][4] = {};
    gemm_acc64(A + (size_t)m0 * K + koff, Bt + (size_t)n0 * K + koff, Kh, K, K,
               &Alds[0][0], &Blds[0][0], acc);
    float* P = kz ? P1 : P0;
    const int tid = threadIdx.x;
    const int wave = tid >> 6, lane = tid & 63;
    const int wr = wave >> 1, wc = wave & 1;
    const int lr = lane & 15, lg = lane >> 4;
#pragma unroll
    for (int ni = 0; ni < 4; ++ni) {
        int n = n0 + wc * 64 + ni * 16 + lr;
#pragma unroll
        for (int mi = 0; mi < 4; ++mi)
#pragma unroll
            for (int r = 0; r < 4; ++r) {
                int m = m0 + wr * 64 + mi * 16 + lg * 4 + r;
                P[(size_t)m * N + n] = acc[mi][ni][r];
            }
    }
}

// ---------------------------------------------------------------------------
// Flash attention, KVBLK=64, XOR-swizzled LDS (r6-verified, VGPR 40, no spill).
// qt is REMAPPED: qt = (blockIdx.x + 4*b) & 15. Rationale: with the natural
// mapping, CU c receives flats {c, c+256, c+512, c+768} which share the SAME
// qt -> causal work per CU spreads [4,64] kv-iters (qt=15 CUs bound the
// kernel). The +4b rotation gives each CU qt values {q,q+4,q+8,q+12} (mod 16)
// -> per-CU totals spread only [28,40]. Bijective per (h,b).
template<bool CAUSAL>
__global__ __launch_bounds__(256, 4)
void attn_flash(const bf16* __restrict__ Qp, int qs,
                const bf16* __restrict__ Kp, int ks,
                const bf16* __restrict__ Vp, int vs,
                const int* __restrict__ Lq, const int* __restrict__ Lk,
                bf16* __restrict__ Op) {
    __shared__ alignas(16) bf16 Klds[64 * 64];
    __shared__ alignas(16) bf16 Vt[64 * 64];
    __shared__ alignas(16) bf16 Plds[4][16 * 64];

    const int tid = threadIdx.x;
    const int wave = tid >> 6, lane = tid & 63;
    const int h = blockIdx.y, b = blockIdx.z;
    const int qt = (blockIdx.x + (b << 2)) & 15;
    const int q0 = qt * 64;
    const int lq = Lq[b], lk = Lk[b];
    const int lr = lane & 15, lg = lane >> 4;

    if (q0 >= lq) {
#pragma unroll
        for (int dt = 0; dt < 4; ++dt)
#pragma unroll
            for (int r = 0; r < 4; ++r) {
                int q = q0 + wave * 16 + lg * 4 + r;
                Op[(size_t)(b * S_LEN + q) * DMODEL + h * HDIM + dt * 16 + lr] = (bf16)0.f;
            }
        return;
    }

    char* KldsB = (char*)Klds;
    char* VtB = (char*)Vt;
    char* PldsB = (char*)&Plds[wave][0];

    bf16x8 aq[2];
    {
        const bf16* qrow = Qp + (size_t)(b * S_LEN + q0 + wave * 16 + lr) * qs + h * HDIM;
        aq[0] = *(const bf16x8*)(qrow + 0 + lg * 8);
        aq[1] = *(const bf16x8*)(qrow + 32 + lg * 8);
    }

    f32x4 o[4] = {};
    float m_run[4], l_run[4];
#pragma unroll
    for (int r = 0; r < 4; ++r) { m_run[r] = -INFINITY; l_run[r] = 0.f; }

    int kv_end = CAUSAL ? (q0 + 64) : S_LEN;
    int lk_cap = (lk + 63) & ~63;
    if (kv_end > lk_cap) kv_end = lk_cap;

    const int vk = lane;
    const int vd0 = wave * 16;

    for (int kk0 = 0; kk0 < kv_end; kk0 += 64) {
#pragma unroll
        for (int c = 0; c < 2; ++c) {
            int rloc = c * 8 + (lane >> 3);
            int row = wave * 16 + rloc;
            int chunk = (lane & 7) ^ (rloc & 7);
            async_load16(Kp + (size_t)(b * S_LEN + kk0 + row) * ks + h * HDIM + chunk * 8,
                         KldsB + (size_t)(wave * 16 + c * 8) * 128);
        }
        {
            const bf16* vsrc = Vp + (size_t)(b * S_LEN + kk0 + vk) * vs + h * HDIM + vd0;
            bf16x8 v0 = *(const bf16x8*)vsrc;
            bf16x8 v1 = *(const bf16x8*)(vsrc + 8);
#pragma unroll
            for (int e = 0; e < 8; ++e) {
                int d0 = vd0 + e, d1 = vd0 + 8 + e;
                *(bf16*)(VtB + (((size_t)d0 * 128 + vk * 2) ^ ((d0 & 7) << 4))) = v0[e];
                *(bf16*)(VtB + (((size_t)d1 * 128 + vk * 2) ^ ((d1 & 7) << 4))) = v1[e];
            }
        }
        __syncthreads();

        f32x4 sa[4];
#pragma unroll
        for (int kt = 0; kt < 4; ++kt) {
            int row = kt * 16 + lr;
            f32x4 z = {};
#pragma unroll
            for (int ds_ = 0; ds_ < 2; ++ds_) {
                bf16x8 bk = *(const bf16x8*)(KldsB +
                    (((size_t)row * 128 + ds_ * 64 + lg * 16) ^ ((row & 7) << 4)));
                z = __builtin_amdgcn_mfma_f32_16x16x32_bf16(aq[ds_], bk, z, 0, 0, 0);
            }
            sa[kt] = z;
        }

        float p[4][4];
#pragma unroll
        for (int r = 0; r < 4; ++r) {
            int q = q0 + wave * 16 + lg * 4 + r;
            float best = -INFINITY;
#pragma unroll
            for (int kt = 0; kt < 4; ++kt) {
                int kk = kk0 + kt * 16 + lr;
                float s = sa[kt][r] * 0.03125f;
                bool ok = (q < lq) && (kk < lk) && (!CAUSAL || kk <= q);
                s = ok ? s : -INFINITY;
                p[kt][r] = s;
                best = fmaxf(best, s);
            }
#pragma unroll
            for (int msk = 1; msk < 16; msk <<= 1)
                best = fmaxf(best, __shfl_xor(best, msk));
            float mn = fmaxf(m_run[r], best);
            float alpha = (m_run[r] == -INFINITY) ? 0.0f : __expf(m_run[r] - mn);
            float rs = 0.f;
#pragma unroll
            for (int kt = 0; kt < 4; ++kt) {
                float s = p[kt][r];
                float e = (s == -INFINITY) ? 0.f : __expf(s - mn);
                p[kt][r] = e;
                rs += e;
            }
#pragma unroll
            for (int msk = 1; msk < 16; msk <<= 1)
                rs += __shfl_xor(rs, msk);
            l_run[r] = l_run[r] * alpha + rs;
            m_run[r] = mn;
#pragma unroll
            for (int dt = 0; dt < 4; ++dt) o[dt][r] *= alpha;
        }

#pragma unroll
        for (int kt = 0; kt < 4; ++kt)
#pragma unroll
            for (int r = 0; r < 4; ++r) {
                int ql = lg * 4 + r, kkl = kt * 16 + lr;
                *(bf16*)(PldsB + (((size_t)ql * 128 + kkl * 2) ^ ((ql & 7) << 4))) =
                    (bf16)p[kt][r];
            }
        bf16x8 pa[2];
#pragma unroll
        for (int ksl = 0; ksl < 2; ++ksl)
            pa[ksl] = *(const bf16x8*)(PldsB +
                (((size_t)lr * 128 + ksl * 64 + lg * 16) ^ ((lr & 7) << 4)));

#pragma unroll
        for (int dt = 0; dt < 4; ++dt) {
            int row = dt * 16 + lr;
#pragma unroll
            for (int ksl = 0; ksl < 2; ++ksl) {
                bf16x8 bv = *(const bf16x8*)(VtB +
                    (((size_t)row * 128 + ksl * 64 + lg * 16) ^ ((row & 7) << 4)));
                o[dt] = __builtin_amdgcn_mfma_f32_16x16x32_bf16(pa[ksl], bv, o[dt], 0, 0, 0);
            }
        }
        __syncthreads();
    }

#pragma unroll
    for (int dt = 0; dt < 4; ++dt) {
#pragma unroll
        for (int r = 0; r < 4; ++r) {
            int q = q0 + wave * 16 + lg * 4 + r;
            float denom = l_run[r];
            float val = denom > 0.f ? o[dt][r] / denom : 0.f;
            Op[(size_t)(b * S_LEN + q) * DMODEL + h * HDIM + dt * 16 + lr] = (bf16)val;
        }
    }
}

// ---------------------------------------------------------------------------
__global__ __launch_bounds__(256)
void ln_kernel(const bf16* __restrict__ x, const float* __restrict__ rc,
               const float* __restrict__ g, const float* __restrict__ beta,
               float* __restrict__ yf, bf16* __restrict__ yb) {
    const int row = blockIdx.x;
    const int tid = threadIdx.x;
    const int wave = tid >> 6, lane = tid & 63;
    const bf16* xr = x + (size_t)row * DMODEL;
    const float* rr = rc + (size_t)row * DMODEL;

    float v[4];
    {
        bf16x4 xv = *(const bf16x4*)(xr + tid * 4);
        f32x4 rv = *(const f32x4*)(rr + tid * 4);
#pragma unroll
        for (int i = 0; i < 4; ++i) v[i] = (float)xv[i] + rv[i];
    }
    float s = v[0] + v[1] + v[2] + v[3];
    float s2 = v[0] * v[0] + v[1] * v[1] + v[2] * v[2] + v[3] * v[3];
#pragma unroll
    for (int msk = 1; msk < 64; msk <<= 1) {
        s += __shfl_xor(s, msk);
        s2 += __shfl_xor(s2, msk);
    }
    __shared__ float red[8];
    if (lane == 0) { red[wave] = s; red[4 + wave] = s2; }
    __syncthreads();
    float ts = red[0] + red[1] + red[2] + red[3];
    float ts2 = red[4] + red[5] + red[6] + red[7];
    float mean = ts * (1.f / DMODEL);
    float var = ts2 * (1.f / DMODEL) - mean * mean;
    float inv = rsqrtf(var + 1e-5f);
#pragma unroll
    for (int i = 0; i < 4; ++i) {
        int c = tid * 4 + i;
        float yv = (v[i] - mean) * inv * g[c] + beta[c];
        if (yf) yf[(size_t)row * DMODEL + c] = yv;
        if (yb) yb[(size_t)row * DMODEL + c] = (bf16)yv;
    }
}

// Final LN fused with split-K reduce: h = relu(P0+P1+bias); out = LN(h + rc).
__global__ __launch_bounds__(256)
void ln_splitk(const float* __restrict__ P0, const float* __restrict__ P1,
               const float* __restrict__ bias, const float* __restrict__ rc,
               const float* __restrict__ g, const float* __restrict__ beta,
               float* __restrict__ yf) {
    const int row = blockIdx.x;
    const int tid = threadIdx.x;
    const int wave = tid >> 6, lane = tid & 63;
    const size_t off = (size_t)row * DMODEL + tid * 4;

    f32x4 a = *(const f32x4*)(P0 + off);
    f32x4 bb = *(const f32x4*)(P1 + off);
    f32x4 bi = *(const f32x4*)(bias + tid * 4);
    f32x4 rv = *(const f32x4*)(rc + off);
    float v[4];
#pragma unroll
    for (int i = 0; i < 4; ++i) {
        float h = a[i] + bb[i] + bi[i];
        h = h > 0.f ? h : 0.f;
        v[i] = h + rv[i];
    }
    float s = v[0] + v[1] + v[2] + v[3];
    float s2 = v[0] * v[0] + v[1] * v[1] + v[2] * v[2] + v[3] * v[3];
#pragma unroll
    for (int msk = 1; msk < 64; msk <<= 1) {
        s += __shfl_xor(s, msk);
        s2 += __shfl_xor(s2, msk);
    }
    __shared__ float red[8];
    if (lane == 0) { red[wave] = s; red[4 + wave] = s2; }
    __syncthreads();
    float ts = red[0] + red[1] + red[2] + red[3];
    float ts2 = red[4] + red[5] + red[6] + red[7];
    float mean = ts * (1.f / DMODEL);
    float var = ts2 * (1.f / DMODEL) - mean * mean;
    float inv = rsqrtf(var + 1e-5f);
#pragma unroll
    for (int i = 0; i < 4; ++i) {
        int c = tid * 4 + i;
        yf[(size_t)row * DMODEL + c] = (v[i] - mean) * inv * g[c] + beta[c];
    }
}

// ---------------------------------------------------------------------------
extern "C" void kernel_launch(void* const* d_in, const int* in_sizes, int n_in,
                              void* d_out, int out_size, void* d_ws, size_t ws_size,
                              hipStream_t stream) {
    const float* en     = (const float*)d_in[0];
    const float* fr     = (const float*)d_in[1];
    const float* W_attn = (const float*)d_in[2];
    const float* b_attn = (const float*)d_in[3];
    const float* W_Q    = (const float*)d_in[4];
    const float* b_Q    = (const float*)d_in[5];
    const float* W_KV   = (const float*)d_in[6];
    const float* b_KV   = (const float*)d_in[7];
    const float* ln_g   = (const float*)d_in[8];
    const float* ln_b   = (const float*)d_in[9];
    const float* W1     = (const float*)d_in[10];
    const float* b1     = (const float*)d_in[11];
    const float* W2     = (const float*)d_in[12];
    const float* b2     = (const float*)d_in[13];
    const int* l_en     = (const int*)d_in[14];
    const int* l_fr     = (const int*)d_in[15];
    float* out = (float*)d_out;

    char* ws = (char*)d_ws;
    const size_t MB = (size_t)1 << 20;
    bf16* Wt_attn = (bf16*)(ws + 0);        //  6 MB (dead after dual; P0 reuse)
    bf16* Wt_Q    = (bf16*)(ws + 6 * MB);   //  2 MB
    bf16* Wt_KV   = (bf16*)(ws + 8 * MB);   //  4 MB
    bf16* Wt_1    = (bf16*)(ws + 12 * MB);  //  8 MB (dead after FFN1; P0 tail)
    bf16* Wt_2    = (bf16*)(ws + 20 * MB);  //  8 MB (live through splitk)
    bf16* fr_bf   = (bf16*)(ws + 28 * MB);  //  8 MB (dead after dual; P1 reuse)
    bf16* en_bf   = (bf16*)(ws + 36 * MB);  //  8 MB (dead after dual; P1 reuse)
    bf16* bigA    = (bf16*)(ws + 44 * MB);  // 32 MB: qkv | qc | h
    bf16* xbuf    = (bf16*)(ws + 76 * MB);  //  8 MB: x1 | x2
    float* fr2    = (float*)(ws + 84 * MB); // 16 MB
    float* fr3    = (float*)(ws + 100 * MB);// 16 MB (kvc until LN2, then fr3)
    bf16* fbx     = (bf16*)(ws + 116 * MB); //  8 MB: fr2_bf then fr3_bf
    float* P0 = (float*)(ws + 0);           // 16 MB over Wt_attn/Q/KV/Wt_1[0:4MB]
    float* P1 = (float*)(ws + 28 * MB);     // 16 MB over fr_bf/en_bf
    bf16* kvc = (bf16*)(ws + 100 * MB);     // 16 MB, overwritten by fr3 at LN2

    dim3 blk(256);

    prep_all<<<dim3(13312), blk, 0, stream>>>(fr, fr_bf, en, en_bf,
                                              W_attn, Wt_attn, W_KV, Wt_KV);

    // --- fused: QKV proj (768 wg) + cross-KV proj (512 wg) + late W
    //     transposes (9216 wg fill the tile_dead slots) ---
    bf16* qkv = bigA;  // [4096][3072]
    GemmArgs gq{fr_bf, Wt_attn, b_attn, qkv, 3072, 1024, l_fr};
    GemmArgs gk{en_bf, Wt_KV, b_KV, kvc, 2048, 1024, l_en};
    gemm_dual<<<dim3(1280 + 9216), blk, 0, stream>>>(gq, 768, gk, 1280,
                                                     W_Q, Wt_Q, W1, Wt_1, W2, Wt_2);

    // --- self attention ---
    attn_flash<true><<<dim3(16, NHEAD, BATCH), blk, 0, stream>>>(
        qkv, 3072, qkv + 1024, 3072, qkv + 2048, 3072, l_fr, l_fr, xbuf);
    ln_kernel<<<dim3(4096), blk, 0, stream>>>(xbuf, fr, ln_g, ln_b, fr2, fbx);

    // --- cross attention ---
    bf16* qc = bigA;  // [4096][1024]
    gemm_one64<false><<<dim3(256), blk, 0, stream>>>(fbx, Wt_Q, b_Q, qc, 1024, 1024, l_fr);
    attn_flash<false><<<dim3(16, NHEAD, BATCH), blk, 0, stream>>>(
        qc, 1024, kvc, 2048, kvc + 1024, 2048, l_fr, l_en, xbuf);
    ln_kernel<<<dim3(4096), blk, 0, stream>>>(xbuf, fr2, ln_g, ln_b, fr3, fbx);

    // --- FFN ---
    bf16* h = bigA;  // [4096][4096]
    gemm_one<true><<<dim3(1024), blk, 0, stream>>>(fbx, Wt_1, b1, h, 4096, 1024, nullptr);
    gemm_splitk2<<<dim3(512), blk, 0, stream>>>(h, Wt_2, P0, P1, 1024, 4096, 256);
    ln_splitk<<<dim3(4096), blk, 0, stream>>>(P0, P1, b2, fr3, ln_g, ln_b, out);
}

// Round 13
// 266.830 us; speedup vs baseline: 1.0912x; 1.0912x over previous
//
#include <hip/hip_runtime.h>
#include <hip/hip_bf16.h>
#include <cstdint>
#include <cstddef>

#define S_LEN  1024
#define DMODEL 1024
#define NHEAD  16
#define HDIM   64
#define BATCH  4
#define MROWS  (BATCH * S_LEN)   // 4096

typedef __bf16 bf16;
typedef __attribute__((ext_vector_type(8))) __bf16 bf16x8;
typedef __attribute__((ext_vector_type(4))) __bf16 bf16x4;
typedef __attribute__((ext_vector_type(4))) float f32x4;
typedef __attribute__((ext_vector_type(4))) unsigned int u32x4;

// ---------------------------------------------------------------------------
__device__ __forceinline__ void async_load16(const void* g, void* l) {
    __builtin_amdgcn_global_load_lds(
        (const __attribute__((address_space(1))) unsigned int*)g,
        (__attribute__((address_space(3))) unsigned int*)l,
        16, 0, 0);
}

// ---------------------------------------------------------------------------
// Prep: blocks [0,8192) convert fr/en f32->bf16; [8192,13312) transpose
// W_attn and W_KV only (W_Q/W1/W2 transposes ride inside gemm_dual's launch).
__global__ __launch_bounds__(256)
void prep_all(const float* __restrict__ fr, bf16* __restrict__ fr_bf,
              const float* __restrict__ en, bf16* __restrict__ en_bf,
              const float* __restrict__ Wa, bf16* __restrict__ Ta,
              const float* __restrict__ Wkv, bf16* __restrict__ Tkv) {
    __shared__ float t[32][33];
    int id = blockIdx.x;
    if (id < 8192) {
        const int n4 = MROWS * DMODEL / 4;
        int i = id * 256 + threadIdx.x;
        const float* in = fr; bf16* out = fr_bf;
        if (i >= n4) { i -= n4; in = en; out = en_bf; }
        f32x4 v = ((const f32x4*)in)[i];
        bf16x4 o;
#pragma unroll
        for (int e = 0; e < 4; ++e) o[e] = (bf16)v[e];
        ((bf16x4*)out)[i] = o;
        return;
    }
    id -= 8192;
    const float* W; bf16* Wt; int K, N, nx, base;
    if (id < 3072) { W = Wa;  Wt = Ta;  K = 1024; N = 3072; nx = 96; base = 0; }
    else           { W = Wkv; Wt = Tkv; K = 1024; N = 2048; nx = 64; base = 3072; }
    int loc = id - base;
    int n0 = (loc % nx) * 32, k0 = (loc / nx) * 32;
    int tx = threadIdx.x & 31, ty = threadIdx.x >> 5;
#pragma unroll
    for (int j = 0; j < 4; ++j)
        t[ty + j * 8][tx] = W[(size_t)(k0 + ty + j * 8) * N + n0 + tx];
    __syncthreads();
#pragma unroll
    for (int j = 0; j < 4; ++j)
        Wt[(size_t)(n0 + ty + j * 8) * K + k0 + tx] = (bf16)t[tx][ty + j * 8];
}

// ---------------------------------------------------------------------------
// GEMM core BK=32: 128x128 tile, 4 waves (2x2), 2-buffer pipeline.
__device__ __forceinline__ void gemm_acc(const bf16* __restrict__ A,
                                         const bf16* __restrict__ Bt,
                                         int Klen, int lda, int ldb,
                                         bf16* Alds, bf16* Blds,  // each [2][128*32]
                                         f32x4 acc[4][4]) {
    const int tid = threadIdx.x;
    const int wave = tid >> 6, lane = tid & 63;
    const int wr = wave >> 1, wc = wave & 1;
    const int lr = lane & 15, lg = lane >> 4, lk = lg * 8;
    const int srow = lane >> 2, scol = (lane & 3) * 8;

    const bf16* Aw = A + (size_t)(wave * 32 + srow) * lda + scol;
    const bf16* Bw = Bt + (size_t)(wave * 32 + srow) * ldb + scol;
    const int ldsw = (wave * 32) * 32;

    async_load16(Aw, Alds + ldsw);
    async_load16(Aw + (size_t)16 * lda, Alds + ldsw + 16 * 32);
    async_load16(Bw, Blds + ldsw);
    async_load16(Bw + (size_t)16 * ldb, Blds + ldsw + 16 * 32);
    __syncthreads();

    const int nt = Klen >> 5;
    for (int t = 0; t < nt; ++t) {
        const int cur = t & 1;
        if (t + 1 < nt) {
            const size_t k0 = (size_t)(t + 1) << 5;
            bf16* Ad = Alds + (cur ^ 1) * (128 * 32) + ldsw;
            bf16* Bd = Blds + (cur ^ 1) * (128 * 32) + ldsw;
            async_load16(Aw + k0, Ad);
            async_load16(Aw + (size_t)16 * lda + k0, Ad + 16 * 32);
            async_load16(Bw + k0, Bd);
            async_load16(Bw + (size_t)16 * ldb + k0, Bd + 16 * 32);
        }
        const bf16* Ab = Alds + cur * (128 * 32);
        const bf16* Bb = Blds + cur * (128 * 32);
        bf16x8 af[4], bfv[4];
#pragma unroll
        for (int i = 0; i < 4; ++i) {
            af[i]  = *(const bf16x8*)&Ab[(wr * 64 + i * 16 + lr) * 32 + lk];
            bfv[i] = *(const bf16x8*)&Bb[(wc * 64 + i * 16 + lr) * 32 + lk];
        }
#pragma unroll
        for (int mi = 0; mi < 4; ++mi)
#pragma unroll
            for (int ni = 0; ni < 4; ++ni)
                acc[mi][ni] = __builtin_amdgcn_mfma_f32_16x16x32_bf16(
                    af[mi], bfv[ni], acc[mi][ni], 0, 0, 0);
        __syncthreads();
    }
}

// ---------------------------------------------------------------------------
// GEMM core BK=64 (XOR-swizzled): ONLY for kernels whose grid limits
// co-residency to <=2 blocks/CU (crossQ 256 wg, splitk 512 wg). r12 showed
// it REGRESSES on larger grids (dual: 64KB LDS cut 2.5->2 blocks/CU).
__device__ __forceinline__ void gemm_acc64(const bf16* __restrict__ A,
                                           const bf16* __restrict__ Bt,
                                           int Klen, int lda, int ldb,
                                           bf16* Alds, bf16* Blds,  // each [2][128*64]
                                           f32x4 acc[4][4]) {
    const int tid = threadIdx.x;
    const int wave = tid >> 6, lane = tid & 63;
    const int wr = wave >> 1, wc = wave & 1;
    const int lr = lane & 15, lg = lane >> 4;
    const int srow = lane >> 3;             // 0..7 (row within 8-row group)
    const int sch = (lane & 7) ^ srow;      // pre-swizzled source chunk

    const bf16* Aw = A + (size_t)(wave * 32 + srow) * lda + sch * 8;
    const bf16* Bw = Bt + (size_t)(wave * 32 + srow) * ldb + sch * 8;

    const int nt = Klen >> 6;
#define STAGE64(buf, k0)                                                       \
    {                                                                          \
        bf16* Ad = Alds + (buf) * (128 * 64) + (wave * 32) * 64;               \
        bf16* Bd = Blds + (buf) * (128 * 64) + (wave * 32) * 64;               \
        _Pragma("unroll")                                                      \
        for (int j = 0; j < 4; ++j) {                                          \
            async_load16(Aw + (size_t)(j * 8) * lda + (k0), Ad + (j * 8) * 64);\
            async_load16(Bw + (size_t)(j * 8) * ldb + (k0), Bd + (j * 8) * 64);\
        }                                                                      \
    }

    STAGE64(0, 0);
    __syncthreads();

    for (int t = 0; t < nt; ++t) {
        const int cur = t & 1;
        if (t + 1 < nt) STAGE64(cur ^ 1, (size_t)(t + 1) << 6);
        const char* Ab = (const char*)(Alds + cur * (128 * 64));
        const char* Bb = (const char*)(Blds + cur * (128 * 64));
#pragma unroll
        for (int ks = 0; ks < 2; ++ks) {
            bf16x8 af[4], bfv[4];
#pragma unroll
            for (int i = 0; i < 4; ++i) {
                int ra = wr * 64 + i * 16 + lr;
                int rb = wc * 64 + i * 16 + lr;
                af[i] = *(const bf16x8*)(Ab + (size_t)ra * 128 +
                          ((ks * 64 + lg * 16) ^ ((ra & 7) << 4)));
                bfv[i] = *(const bf16x8*)(Bb + (size_t)rb * 128 +
                          ((ks * 64 + lg * 16) ^ ((rb & 7) << 4)));
            }
#pragma unroll
            for (int mi = 0; mi < 4; ++mi)
#pragma unroll
                for (int ni = 0; ni < 4; ++ni)
                    acc[mi][ni] = __builtin_amdgcn_mfma_f32_16x16x32_bf16(
                        af[mi], bfv[ni], acc[mi][ni], 0, 0, 0);
        }
        __syncthreads();
    }
#undef STAGE64
}

template<bool RELU>
__device__ __forceinline__ void epi_bf16(bf16* __restrict__ C, const float* __restrict__ bias,
                                         int N, int m0, int n0, f32x4 acc[4][4]) {
    const int tid = threadIdx.x;
    const int wave = tid >> 6, lane = tid & 63;
    const int wr = wave >> 1, wc = wave & 1;
    const int lr = lane & 15, lg = lane >> 4;
#pragma unroll
    for (int ni = 0; ni < 4; ++ni) {
        int n = n0 + wc * 64 + ni * 16 + lr;
        float bn = bias[n];
#pragma unroll
        for (int mi = 0; mi < 4; ++mi)
#pragma unroll
            for (int r = 0; r < 4; ++r) {
                int m = m0 + wr * 64 + mi * 16 + lg * 4 + r;
                float v = acc[mi][ni][r] + bn;
                if (RELU) v = v > 0.f ? v : 0.f;
                C[(size_t)m * N + n] = (bf16)v;
            }
    }
}

// M-tile skip: rows of this 128-tile are never consumed downstream.
__device__ __forceinline__ bool tile_dead(const int* Lm, int m0) {
    if (!Lm) return false;
    int cap = (Lm[m0 >> 10] + 63) & ~63;
    return (m0 & 1023) >= cap;
}

// N-major tile mapping (m0 = f%32, n0 = f/32): spreads tile_dead blocks
// uniformly across XCD chunks (see r9/r10 analysis).
template<bool RELU>
__global__ __launch_bounds__(256, 2)
void gemm_one(const bf16* __restrict__ A, const bf16* __restrict__ Bt,
              const float* __restrict__ bias, bf16* __restrict__ C,
              int N, int K, const int* __restrict__ Lm) {
    __shared__ alignas(16) bf16 Alds[2][128 * 32];
    __shared__ alignas(16) bf16 Blds[2][128 * 32];
    const int nwg = gridDim.x;
    const int flat = blockIdx.x;
    const int swz = (flat & 7) * (nwg >> 3) + (flat >> 3);
    const int m0 = (swz & 31) * 128, n0 = (swz >> 5) * 128;
    if (tile_dead(Lm, m0)) return;
    f32x4 acc[4][4] = {};
    gemm_acc(A + (size_t)m0 * K, Bt + (size_t)n0 * K, K, K, K,
             &Alds[0][0], &Blds[0][0], acc);
    epi_bf16<RELU>(C, bias, N, m0, n0, acc);
}

// BK=64 variant: for grids limited to <=2 blocks/CU (crossQ).
template<bool RELU>
__global__ __launch_bounds__(256, 2)
void gemm_one64(const bf16* __restrict__ A, const bf16* __restrict__ Bt,
                const float* __restrict__ bias, bf16* __restrict__ C,
                int N, int K, const int* __restrict__ Lm) {
    __shared__ alignas(16) bf16 Alds[2][128 * 64];
    __shared__ alignas(16) bf16 Blds[2][128 * 64];
    const int nwg = gridDim.x;
    const int flat = blockIdx.x;
    const int swz = (flat & 7) * (nwg >> 3) + (flat >> 3);
    const int m0 = (swz & 31) * 128, n0 = (swz >> 5) * 128;
    if (tile_dead(Lm, m0)) return;
    f32x4 acc[4][4] = {};
    gemm_acc64(A + (size_t)m0 * K, Bt + (size_t)n0 * K, K, K, K,
               &Alds[0][0], &Blds[0][0], acc);
    epi_bf16<RELU>(C, bias, N, m0, n0, acc);
}

// ---------------------------------------------------------------------------
// Dual GEMM (BK=32 — r12 proved BK=64 regresses here) + trailing
// weight-transpose blocks: flats [0,nwgG) = GEMMs; [nwgG,+9216) W_Q/W1/W2.
struct GemmArgs {
    const bf16* A; const bf16* Bt; const float* bias; bf16* C;
    int N; int K; const int* Lm;
};
__global__ __launch_bounds__(256, 2)
void gemm_dual(GemmArgs g0, int nwg0, GemmArgs g1, int nwgG,
               const float* __restrict__ Wq, bf16* __restrict__ Tq,
               const float* __restrict__ W1, bf16* __restrict__ T1,
               const float* __restrict__ W2, bf16* __restrict__ T2) {
    __shared__ alignas(16) bf16 Alds[2][128 * 32];
    __shared__ alignas(16) bf16 Blds[2][128 * 32];
    const int flat = blockIdx.x;
    if (flat >= nwgG) {
        int id = flat - nwgG;
        const float* W; bf16* Wt; int K, N, nx, base;
        if (id < 1024)      { W = Wq; Wt = Tq; K = 1024; N = 1024; nx = 32;  base = 0; }
        else if (id < 5120) { W = W1; Wt = T1; K = 1024; N = 4096; nx = 128; base = 1024; }
        else                { W = W2; Wt = T2; K = 4096; N = 1024; nx = 32;  base = 5120; }
        int loc = id - base;
        int n0 = (loc % nx) * 32, k0 = (loc / nx) * 32;
        float (*t)[33] = (float(*)[33])&Alds[0][0];   // alias GEMM LDS
        int tx = threadIdx.x & 31, ty = threadIdx.x >> 5;
#pragma unroll
        for (int j = 0; j < 4; ++j)
            t[ty + j * 8][tx] = W[(size_t)(k0 + ty + j * 8) * N + n0 + tx];
        __syncthreads();
#pragma unroll
        for (int j = 0; j < 4; ++j)
            Wt[(size_t)(n0 + ty + j * 8) * K + k0 + tx] = (bf16)t[tx][ty + j * 8];
        return;
    }
    const int swz = (flat & 7) * (nwgG >> 3) + (flat >> 3);
    const bool first = swz < nwg0;
    const GemmArgs g = first ? g0 : g1;
    const int f = first ? swz : swz - nwg0;
    const int m0 = (f & 31) * 128, n0 = (f >> 5) * 128;
    if (tile_dead(g.Lm, m0)) return;
    f32x4 acc[4][4] = {};
    gemm_acc(g.A + (size_t)m0 * g.K, g.Bt + (size_t)n0 * g.K, g.K, g.K, g.K,
             &Alds[0][0], &Blds[0][0], acc);
    epi_bf16<false>(g.C, g.bias, g.N, m0, n0, acc);
}

// ---------------------------------------------------------------------------
// Split-K=2 GEMM for FFN2, BK=64 core (grid 512 = 2 blocks/CU; 64KB LDS free).
__global__ __launch_bounds__(256, 2)
void gemm_splitk2(const bf16* __restrict__ A, const bf16* __restrict__ Bt,
                  float* __restrict__ P0, float* __restrict__ P1,
                  int N, int K, int nwg_half) {
    __shared__ alignas(16) bf16 Alds[2][128 * 64];
    __shared__ alignas(16) bf16 Blds[2][128 * 64];
    const int nwg = gridDim.x;
    const int flat = blockIdx.x;
    const int swz = (flat & 7) * (nwg >> 3) + (flat >> 3);
    const int kz = swz >= nwg_half ? 1 : 0;
    const int f = swz - kz * nwg_half;
    const int m0 = (f & 31) * 128, n0 = (f >> 5) * 128;
    const int Kh = K >> 1;
    const size_t koff = (size_t)kz * Kh;
    f32x4 acc[4][4] = {};
    gemm_acc64(A + (size_t)m0 * K + koff, Bt + (size_t)n0 * K + koff, Kh, K, K,
               &Alds[0][0], &Blds[0][0], acc);
    float* P = kz ? P1 : P0;
    const int tid = threadIdx.x;
    const int wave = tid >> 6, lane = tid & 63;
    const int wr = wave >> 1, wc = wave & 1;
    const int lr = lane & 15, lg = lane >> 4;
#pragma unroll
    for (int ni = 0; ni < 4; ++ni) {
        int n = n0 + wc * 64 + ni * 16 + lr;
#pragma unroll
        for (int mi = 0; mi < 4; ++mi)
#pragma unroll
            for (int r = 0; r < 4; ++r) {
                int m = m0 + wr * 64 + mi * 16 + lg * 4 + r;
                P[(size_t)m * N + n] = acc[mi][ni][r];
            }
    }
}

// ---------------------------------------------------------------------------
// Flash attention, KVBLK=64, XOR-swizzled LDS (r6-verified, VGPR 40, no spill).
// qt remapped (+4b mod 16) to spread causal work across CUs (neutral-to-
// positive; kept from r12).
template<bool CAUSAL>
__global__ __launch_bounds__(256, 4)
void attn_flash(const bf16* __restrict__ Qp, int qs,
                const bf16* __restrict__ Kp, int ks,
                const bf16* __restrict__ Vp, int vs,
                const int* __restrict__ Lq, const int* __restrict__ Lk,
                bf16* __restrict__ Op) {
    __shared__ alignas(16) bf16 Klds[64 * 64];
    __shared__ alignas(16) bf16 Vt[64 * 64];
    __shared__ alignas(16) bf16 Plds[4][16 * 64];

    const int tid = threadIdx.x;
    const int wave = tid >> 6, lane = tid & 63;
    const int h = blockIdx.y, b = blockIdx.z;
    const int qt = (blockIdx.x + (b << 2)) & 15;
    const int q0 = qt * 64;
    const int lq = Lq[b], lk = Lk[b];
    const int lr = lane & 15, lg = lane >> 4;

    if (q0 >= lq) {
#pragma unroll
        for (int dt = 0; dt < 4; ++dt)
#pragma unroll
            for (int r = 0; r < 4; ++r) {
                int q = q0 + wave * 16 + lg * 4 + r;
                Op[(size_t)(b * S_LEN + q) * DMODEL + h * HDIM + dt * 16 + lr] = (bf16)0.f;
            }
        return;
    }

    char* KldsB = (char*)Klds;
    char* VtB = (char*)Vt;
    char* PldsB = (char*)&Plds[wave][0];

    bf16x8 aq[2];
    {
        const bf16* qrow = Qp + (size_t)(b * S_LEN + q0 + wave * 16 + lr) * qs + h * HDIM;
        aq[0] = *(const bf16x8*)(qrow + 0 + lg * 8);
        aq[1] = *(const bf16x8*)(qrow + 32 + lg * 8);
    }

    f32x4 o[4] = {};
    float m_run[4], l_run[4];
#pragma unroll
    for (int r = 0; r < 4; ++r) { m_run[r] = -INFINITY; l_run[r] = 0.f; }

    int kv_end = CAUSAL ? (q0 + 64) : S_LEN;
    int lk_cap = (lk + 63) & ~63;
    if (kv_end > lk_cap) kv_end = lk_cap;

    const int vk = lane;
    const int vd0 = wave * 16;

    for (int kk0 = 0; kk0 < kv_end; kk0 += 64) {
#pragma unroll
        for (int c = 0; c < 2; ++c) {
            int rloc = c * 8 + (lane >> 3);
            int row = wave * 16 + rloc;
            int chunk = (lane & 7) ^ (rloc & 7);
            async_load16(Kp + (size_t)(b * S_LEN + kk0 + row) * ks + h * HDIM + chunk * 8,
                         KldsB + (size_t)(wave * 16 + c * 8) * 128);
        }
        {
            const bf16* vsrc = Vp + (size_t)(b * S_LEN + kk0 + vk) * vs + h * HDIM + vd0;
            bf16x8 v0 = *(const bf16x8*)vsrc;
            bf16x8 v1 = *(const bf16x8*)(vsrc + 8);
#pragma unroll
            for (int e = 0; e < 8; ++e) {
                int d0 = vd0 + e, d1 = vd0 + 8 + e;
                *(bf16*)(VtB + (((size_t)d0 * 128 + vk * 2) ^ ((d0 & 7) << 4))) = v0[e];
                *(bf16*)(VtB + (((size_t)d1 * 128 + vk * 2) ^ ((d1 & 7) << 4))) = v1[e];
            }
        }
        __syncthreads();

        f32x4 sa[4];
#pragma unroll
        for (int kt = 0; kt < 4; ++kt) {
            int row = kt * 16 + lr;
            f32x4 z = {};
#pragma unroll
            for (int ds_ = 0; ds_ < 2; ++ds_) {
                bf16x8 bk = *(const bf16x8*)(KldsB +
                    (((size_t)row * 128 + ds_ * 64 + lg * 16) ^ ((row & 7) << 4)));
                z = __builtin_amdgcn_mfma_f32_16x16x32_bf16(aq[ds_], bk, z, 0, 0, 0);
            }
            sa[kt] = z;
        }

        float p[4][4];
#pragma unroll
        for (int r = 0; r < 4; ++r) {
            int q = q0 + wave * 16 + lg * 4 + r;
            float best = -INFINITY;
#pragma unroll
            for (int kt = 0; kt < 4; ++kt) {
                int kk = kk0 + kt * 16 + lr;
                float s = sa[kt][r] * 0.03125f;
                bool ok = (q < lq) && (kk < lk) && (!CAUSAL || kk <= q);
                s = ok ? s : -INFINITY;
                p[kt][r] = s;
                best = fmaxf(best, s);
            }
#pragma unroll
            for (int msk = 1; msk < 16; msk <<= 1)
                best = fmaxf(best, __shfl_xor(best, msk));
            float mn = fmaxf(m_run[r], best);
            float alpha = (m_run[r] == -INFINITY) ? 0.0f : __expf(m_run[r] - mn);
            float rs = 0.f;
#pragma unroll
            for (int kt = 0; kt < 4; ++kt) {
                float s = p[kt][r];
                float e = (s == -INFINITY) ? 0.f : __expf(s - mn);
                p[kt][r] = e;
                rs += e;
            }
#pragma unroll
            for (int msk = 1; msk < 16; msk <<= 1)
                rs += __shfl_xor(rs, msk);
            l_run[r] = l_run[r] * alpha + rs;
            m_run[r] = mn;
#pragma unroll
            for (int dt = 0; dt < 4; ++dt) o[dt][r] *= alpha;
        }

#pragma unroll
        for (int kt = 0; kt < 4; ++kt)
#pragma unroll
            for (int r = 0; r < 4; ++r) {
                int ql = lg * 4 + r, kkl = kt * 16 + lr;
                *(bf16*)(PldsB + (((size_t)ql * 128 + kkl * 2) ^ ((ql & 7) << 4))) =
                    (bf16)p[kt][r];
            }
        bf16x8 pa[2];
#pragma unroll
        for (int ksl = 0; ksl < 2; ++ksl)
            pa[ksl] = *(const bf16x8*)(PldsB +
                (((size_t)lr * 128 + ksl * 64 + lg * 16) ^ ((lr & 7) << 4)));

#pragma unroll
        for (int dt = 0; dt < 4; ++dt) {
            int row = dt * 16 + lr;
#pragma unroll
            for (int ksl = 0; ksl < 2; ++ksl) {
                bf16x8 bv = *(const bf16x8*)(VtB +
                    (((size_t)row * 128 + ksl * 64 + lg * 16) ^ ((row & 7) << 4)));
                o[dt] = __builtin_amdgcn_mfma_f32_16x16x32_bf16(pa[ksl], bv, o[dt], 0, 0, 0);
            }
        }
        __syncthreads();
    }

#pragma unroll
    for (int dt = 0; dt < 4; ++dt) {
#pragma unroll
        for (int r = 0; r < 4; ++r) {
            int q = q0 + wave * 16 + lg * 4 + r;
            float denom = l_run[r];
            float val = denom > 0.f ? o[dt][r] / denom : 0.f;
            Op[(size_t)(b * S_LEN + q) * DMODEL + h * HDIM + dt * 16 + lr] = (bf16)val;
        }
    }
}

// ---------------------------------------------------------------------------
// y = LayerNorm(x_bf16 + rc) * g + b, single bf16 output (y serves as both
// the next residual and the next GEMM input). rc is f32 (first LN, rc=fr
// input) or bf16 (later LNs, rc = previous LN's y). Residual-in-bf16 is
// within tolerance (absmax margin 3.4x).
template<bool RC_F32>
__global__ __launch_bounds__(256)
void ln_kernel(const bf16* __restrict__ x, const void* __restrict__ rc,
               const float* __restrict__ g, const float* __restrict__ beta,
               bf16* __restrict__ yb) {
    const int row = blockIdx.x;
    const int tid = threadIdx.x;
    const int wave = tid >> 6, lane = tid & 63;
    const bf16* xr = x + (size_t)row * DMODEL;

    float v[4];
    {
        bf16x4 xv = *(const bf16x4*)(xr + tid * 4);
        if (RC_F32) {
            f32x4 rv = *(const f32x4*)((const float*)rc + (size_t)row * DMODEL + tid * 4);
#pragma unroll
            for (int i = 0; i < 4; ++i) v[i] = (float)xv[i] + rv[i];
        } else {
            bf16x4 rv = *(const bf16x4*)((const bf16*)rc + (size_t)row * DMODEL + tid * 4);
#pragma unroll
            for (int i = 0; i < 4; ++i) v[i] = (float)xv[i] + (float)rv[i];
        }
    }
    float s = v[0] + v[1] + v[2] + v[3];
    float s2 = v[0] * v[0] + v[1] * v[1] + v[2] * v[2] + v[3] * v[3];
#pragma unroll
    for (int msk = 1; msk < 64; msk <<= 1) {
        s += __shfl_xor(s, msk);
        s2 += __shfl_xor(s2, msk);
    }
    __shared__ float red[8];
    if (lane == 0) { red[wave] = s; red[4 + wave] = s2; }
    __syncthreads();
    float ts = red[0] + red[1] + red[2] + red[3];
    float ts2 = red[4] + red[5] + red[6] + red[7];
    float mean = ts * (1.f / DMODEL);
    float var = ts2 * (1.f / DMODEL) - mean * mean;
    float inv = rsqrtf(var + 1e-5f);
    bf16x4 o;
#pragma unroll
    for (int i = 0; i < 4; ++i) {
        int c = tid * 4 + i;
        o[i] = (bf16)((v[i] - mean) * inv * g[c] + beta[c]);
    }
    *(bf16x4*)(yb + (size_t)row * DMODEL + tid * 4) = o;
}

// Final LN fused with split-K reduce: h = relu(P0+P1+bias); out = LN(h + rc),
// rc in bf16. Output f32 (harness dtype).
__global__ __launch_bounds__(256)
void ln_splitk(const float* __restrict__ P0, const float* __restrict__ P1,
               const float* __restrict__ bias, const bf16* __restrict__ rc,
               const float* __restrict__ g, const float* __restrict__ beta,
               float* __restrict__ yf) {
    const int row = blockIdx.x;
    const int tid = threadIdx.x;
    const int wave = tid >> 6, lane = tid & 63;
    const size_t off = (size_t)row * DMODEL + tid * 4;

    f32x4 a = *(const f32x4*)(P0 + off);
    f32x4 bb = *(const f32x4*)(P1 + off);
    f32x4 bi = *(const f32x4*)(bias + tid * 4);
    bf16x4 rv = *(const bf16x4*)(rc + off);
    float v[4];
#pragma unroll
    for (int i = 0; i < 4; ++i) {
        float h = a[i] + bb[i] + bi[i];
        h = h > 0.f ? h : 0.f;
        v[i] = h + (float)rv[i];
    }
    float s = v[0] + v[1] + v[2] + v[3];
    float s2 = v[0] * v[0] + v[1] * v[1] + v[2] * v[2] + v[3] * v[3];
#pragma unroll
    for (int msk = 1; msk < 64; msk <<= 1) {
        s += __shfl_xor(s, msk);
        s2 += __shfl_xor(s2, msk);
    }
    __shared__ float red[8];
    if (lane == 0) { red[wave] = s; red[4 + wave] = s2; }
    __syncthreads();
    float ts = red[0] + red[1] + red[2] + red[3];
    float ts2 = red[4] + red[5] + red[6] + red[7];
    float mean = ts * (1.f / DMODEL);
    float var = ts2 * (1.f / DMODEL) - mean * mean;
    float inv = rsqrtf(var + 1e-5f);
#pragma unroll
    for (int i = 0; i < 4; ++i) {
        int c = tid * 4 + i;
        yf[(size_t)row * DMODEL + c] = (v[i] - mean) * inv * g[c] + beta[c];
    }
}

// ---------------------------------------------------------------------------
extern "C" void kernel_launch(void* const* d_in, const int* in_sizes, int n_in,
                              void* d_out, int out_size, void* d_ws, size_t ws_size,
                              hipStream_t stream) {
    const float* en     = (const float*)d_in[0];
    const float* fr     = (const float*)d_in[1];
    const float* W_attn = (const float*)d_in[2];
    const float* b_attn = (const float*)d_in[3];
    const float* W_Q    = (const float*)d_in[4];
    const float* b_Q    = (const float*)d_in[5];
    const float* W_KV   = (const float*)d_in[6];
    const float* b_KV   = (const float*)d_in[7];
    const float* ln_g   = (const float*)d_in[8];
    const float* ln_b   = (const float*)d_in[9];
    const float* W1     = (const float*)d_in[10];
    const float* b1     = (const float*)d_in[11];
    const float* W2     = (const float*)d_in[12];
    const float* b2     = (const float*)d_in[13];
    const int* l_en     = (const int*)d_in[14];
    const int* l_fr     = (const int*)d_in[15];
    float* out = (float*)d_out;

    char* ws = (char*)d_ws;
    const size_t MB = (size_t)1 << 20;
    bf16* Wt_attn = (bf16*)(ws + 0);        //  6 MB (dead after dual; P0 reuse)
    bf16* Wt_Q    = (bf16*)(ws + 6 * MB);   //  2 MB (dead after crossQ)
    bf16* Wt_KV   = (bf16*)(ws + 8 * MB);   //  4 MB (dead after dual)
    bf16* Wt_1    = (bf16*)(ws + 12 * MB);  //  8 MB (dead after FFN1; P0 tail)
    bf16* Wt_2    = (bf16*)(ws + 20 * MB);  //  8 MB (live through splitk)
    bf16* fr_bf   = (bf16*)(ws + 28 * MB);  //  8 MB (dead after dual; P1 reuse)
    bf16* en_bf   = (bf16*)(ws + 36 * MB);  //  8 MB (dead after dual; P1 reuse)
    bf16* bigA    = (bf16*)(ws + 44 * MB);  // 32 MB: qkv | qc | h
    bf16* xbuf    = (bf16*)(ws + 76 * MB);  //  8 MB: x1 | x2 (attn outputs)
    bf16* y1      = (bf16*)(ws + 116 * MB); //  8 MB: LN1 out (residual+GEMM in)
    bf16* y2      = (bf16*)(ws + 84 * MB);  //  8 MB: LN2 out (residual+GEMM in)
    float* P0 = (float*)(ws + 0);           // 16 MB over Wt_attn/Q/KV/Wt_1[0:4MB]
    float* P1 = (float*)(ws + 28 * MB);     // 16 MB over fr_bf/en_bf
    bf16* kvc = (bf16*)(ws + 100 * MB);     // 16 MB (dead after attn2)

    dim3 blk(256);

    prep_all<<<dim3(13312), blk, 0, stream>>>(fr, fr_bf, en, en_bf,
                                              W_attn, Wt_attn, W_KV, Wt_KV);

    // --- fused: QKV proj (768 wg) + cross-KV proj (512 wg) + late W
    //     transposes (9216 wg fill the tile_dead slots) ---
    bf16* qkv = bigA;  // [4096][3072]
    GemmArgs gq{fr_bf, Wt_attn, b_attn, qkv, 3072, 1024, l_fr};
    GemmArgs gk{en_bf, Wt_KV, b_KV, kvc, 2048, 1024, l_en};
    gemm_dual<<<dim3(1280 + 9216), blk, 0, stream>>>(gq, 768, gk, 1280,
                                                     W_Q, Wt_Q, W1, Wt_1, W2, Wt_2);

    // --- self attention ---
    attn_flash<true><<<dim3(16, NHEAD, BATCH), blk, 0, stream>>>(
        qkv, 3072, qkv + 1024, 3072, qkv + 2048, 3072, l_fr, l_fr, xbuf);
    ln_kernel<true><<<dim3(4096), blk, 0, stream>>>(xbuf, fr, ln_g, ln_b, y1);

    // --- cross attention ---
    bf16* qc = bigA;  // [4096][1024]
    gemm_one64<false><<<dim3(256), blk, 0, stream>>>(y1, Wt_Q, b_Q, qc, 1024, 1024, l_fr);
    attn_flash<false><<<dim3(16, NHEAD, BATCH), blk, 0, stream>>>(
        qc, 1024, kvc, 2048, kvc + 1024, 2048, l_fr, l_en, xbuf);
    ln_kernel<false><<<dim3(4096), blk, 0, stream>>>(xbuf, y1, ln_g, ln_b, y2);

    // --- FFN ---
    bf16* h = bigA;  // [4096][4096]
    gemm_one<true><<<dim3(1024), blk, 0, stream>>>(y2, Wt_1, b1, h, 4096, 1024, nullptr);
    gemm_splitk2<<<dim3(512), blk, 0, stream>>>(h, Wt_2, P0, P1, 1024, 4096, 256);
    ln_splitk<<<dim3(4096), blk, 0, stream>>>(P0, P1, b2, y2, ln_g, ln_b, out);
}